// Round 11
// baseline (491.011 us; speedup 1.0000x reference)
//
#include <hip/hip_runtime.h>
#include <stdint.h>

#define B_ 32
#define S_ 2048
#define D_ 64
// q pre-scale: 1/8 (temperature) * log2(e) so exp2(acc) == exp(S/8)
#define QSCALE 0.18033688011112042f

typedef __attribute__((ext_vector_type(8)))  short short8v;
typedef __attribute__((ext_vector_type(4)))  short short4v;
typedef __attribute__((ext_vector_type(4)))  float f32x4;
typedef __attribute__((ext_vector_type(16))) float f32x16;
typedef __attribute__((ext_vector_type(4)))  float float4v;
typedef __attribute__((ext_vector_type(4)))  int int4v;

static __device__ inline short f2bf(float f){
  uint32_t u = __builtin_bit_cast(uint32_t, f);
  uint32_t r = (u + 0x7fffu + ((u >> 16) & 1u)) >> 16;
  return (short)(uint16_t)r;
}

static __device__ inline void gl16(const void* g, void* l){
  __builtin_amdgcn_global_load_lds(
      (const __attribute__((address_space(1))) void*)g,
      (__attribute__((address_space(3))) void*)l, 16, 0, 0);
}

static __device__ inline uint32_t pkbf(float lo, float hi){
  uint32_t w;
  asm("v_cvt_pk_bf16_f32 %0, %1, %2" : "=v"(w) : "v"(lo), "v"(hi));
  return w;
}

// ---- kernel 0a: q (pre-scaled by log2e/8) and k -> bf16 row-major ----
__global__ __launch_bounds__(256) void cvt_qk(const float* __restrict__ q,
                                              const float* __restrict__ k,
                                              short* __restrict__ qb,
                                              short* __restrict__ kb){
  size_t i = ((size_t)blockIdx.x * 256 + threadIdx.x) * 4;
  float4v a = *(const float4v*)(q + i);
  float4v c = *(const float4v*)(k + i);
  short4v qa = { f2bf(a[0]*QSCALE), f2bf(a[1]*QSCALE), f2bf(a[2]*QSCALE), f2bf(a[3]*QSCALE) };
  short4v kc = { f2bf(c[0]), f2bf(c[1]), f2bf(c[2]), f2bf(c[3]) };
  *(short4v*)(qb + i) = qa;
  *(short4v*)(kb + i) = kc;
}

// ---- kernel 0b: v -> bf16 transposed + k bit2/3-permuted: vbT[b][d][k'] ----
__global__ __launch_bounds__(256) void cvt_v(const float* __restrict__ v,
                                             short* __restrict__ vbT){
  __shared__ float tile[64][65];
  int b = blockIdx.y, st = blockIdx.x;
  int tid = threadIdx.x;
#pragma unroll
  for (int i = 0; i < 4; i++){
    int s = tid + i*256;
    int row = s >> 4, c4 = (s & 15) * 4;
    float4v t = *(const float4v*)(v + ((size_t)b*S_ + st*64 + row)*D_ + c4);
    tile[row][c4+0] = t[0]; tile[row][c4+1] = t[1];
    tile[row][c4+2] = t[2]; tile[row][c4+3] = t[3];
  }
  __syncthreads();
#pragma unroll
  for (int i = 0; i < 2; i++){
    int s = tid + i*256;
    int d = s >> 3, s8 = (s & 7) * 8;
    short8v o;
#pragma unroll
    for (int j = 0; j < 8; j++){
      int y = s8 + j;
      int ysrc = (y & ~12) | ((y & 4) << 1) | ((y & 8) >> 1);  // swap bits 2,3
      o[j] = f2bf(tile[ysrc][d]);
    }
    *(short8v*)(vbT + ((size_t)b*D_ + d)*S_ + st*64 + s8) = o;
  }
}

// ---- main fused kernel: 16 waves/CU via k-split wave pairs ----
// 1024 thr (16 waves), 256 q/block, grid (8,32) = 256 blocks = 1/CU.
// wave w: q-tile qt=w>>1 (32 rows), k-half=w&1 (1024 k, 16 stages of 64).
// LDS: K 2strm x 2buf x 8K @0 | V same @32K | bits 16w x 4K @64K | lrun @128K
#define WAITN(n) asm volatile("s_waitcnt vmcnt(" #n ")" ::: "memory")
#define LGKM0    asm volatile("s_waitcnt lgkmcnt(0)" ::: "memory")
#define BAR   __builtin_amdgcn_s_barrier()

__global__ __launch_bounds__(1024, 1) void attn_fused(
    const short* __restrict__ qb, const short* __restrict__ kb,
    const short* __restrict__ vbT, const int* __restrict__ mask,
    float* __restrict__ outp, float* __restrict__ attn)
{
  __shared__ __align__(16) char lds[133120];
  const int tid  = threadIdx.x;
  const int w    = tid >> 6;
  const int lane = tid & 63;
  const int l31  = lane & 31;          // q within wave tile / C-col
  const int h    = lane >> 5;          // lane half (MFMA reg split)
  const int h4   = h * 4;
  const int h16  = h * 16;
  const int half = w & 1;              // k-half of this wave
  const int qt   = w >> 1;             // q-tile 0..7
  const int sl   = w >> 1;             // DMA slice 0..7 within the 8KB tile
  const int hoff = half * 1024;        // k offset of this wave's half

  const int b    = blockIdx.y;
  const int q0b  = blockIdx.x * 256;
  const int qrow = q0b + qt*32 + l31;

  const short* kbb = kb  + (size_t)b*S_*D_;
  const short* vbb = vbT + (size_t)b*D_*S_;

  // per-lane DMA sources (pre-swizzled; LDS dest linear chunk order)
  const int rowl = sl*8 + (lane >> 3);          // 0..63 within tile
  const int c8   = (lane & 7) ^ (rowl & 7);     // swizzled 16B chunk in row
  const short* kSrc = kbb + (size_t)(hoff + rowl)*D_ + c8*8;  // +t*64*D_/stage
  const short* vSrc = vbb + (size_t)rowl*S_ + hoff + c8*8;    // +t*64/stage
  const int sloff = sl << 10;                   // 1KB slice in tile

  // Q B-fragments: qf[dc] holds Q[qrow][d = 16dc + 8h + e]
  const size_t qoff = ((size_t)b*S_ + qrow) * D_;
  short8v qf[4];
#pragma unroll
  for (int dc = 0; dc < 4; dc++)
    qf[dc] = *(const short8v*)(qb + qoff + dc*16 + h*8);

  const int* mrow = mask + ((size_t)b*S_ + qrow)*S_ + hoff;
  float* aRow = attn + ((size_t)b*S_ + qrow)*S_ + hoff;

  uint32_t* sMB  = (uint32_t*)(lds + 65536 + (w << 12));   // 16 st x 64 lanes
  float*    lrS  = (float*)(lds + 131072);                 // 8 qt x 64

  auto ISSK = [&](int t){
    gl16(kSrc + (size_t)(t<<6)*D_, lds + half*16384 + ((t&1)<<13) + sloff); };
  auto ISSV = [&](int t){
    gl16(vSrc + (t<<6), lds + 32768 + half*16384 + ((t&1)<<13) + sloff); };

#define LOADM(mv, t) do{ const int _ks = (t) << 6; \
    _Pragma("unroll") \
    for (int _i = 0; _i < 8; _i++) \
      mv[_i] = *(const int4v*)(mrow + _ks + (_i>>2)*32 + (_i&3)*8 + h4); }while(0)

  float lrun = 0.f;

#define COMPUTE1(t, mv) do{ \
    const char* sKc = lds + half*16384 + (((t) & 1) << 13); \
    uint32_t bits = 0; \
    _Pragma("unroll") \
    for (int Tt = 0; Tt < 2; Tt++){ \
      const int row = l31 + 32*Tt; \
      const char* kr = sKc + row*128; \
      const int sw = (row & 7) << 4; \
      f32x16 acc = {0.f,0.f,0.f,0.f,0.f,0.f,0.f,0.f,0.f,0.f,0.f,0.f,0.f,0.f,0.f,0.f}; \
      _Pragma("unroll") \
      for (int dc = 0; dc < 4; dc++){ \
        short8v ka = *(const short8v*)(kr + ((dc*32 + h16) ^ sw)); \
        acc = __builtin_amdgcn_mfma_f32_32x32x16_bf16(ka, qf[dc], acc, 0,0,0); \
      } \
      _Pragma("unroll") \
      for (int u = 0; u < 4; u++){ \
        int4v mu = mv[Tt*4 + u]; \
        uint32_t nib = (mu[0]?1u:0u)|(mu[1]?2u:0u)|(mu[2]?4u:0u)|(mu[3]?8u:0u); \
        bits |= nib << ((Tt*4 + u)*4); \
        float e0 = (nib & 1u) ? 0.f : exp2f(acc[4*u+0]); \
        float e1 = (nib & 2u) ? 0.f : exp2f(acc[4*u+1]); \
        float e2 = (nib & 4u) ? 0.f : exp2f(acc[4*u+2]); \
        float e3 = (nib & 8u) ? 0.f : exp2f(acc[4*u+3]); \
        lrun += (e0 + e1) + (e2 + e3); \
      } \
    } \
    sMB[((t) << 6) + lane] = bits; }while(0)

  // ========== sweep 1: 16 stages over this wave's k-half ==========
  int4v mA[8], mB[8];
  ISSK(0); LOADM(mA, 0); LOADM(mB, 1);
  WAITN(8); BAR; ISSK(1); COMPUTE1(0, mA); LOADM(mA, 2);
  for (int t = 1; t < 15; t += 2){
    WAITN(8); BAR; ISSK(t+1); COMPUTE1(t, mB);
    if (t+2 < 16) LOADM(mB, t+2);
    WAITN(8); BAR;
    if (t+2 < 16) ISSK(t+2);
    COMPUTE1(t+1, mA);
    if (t+3 < 16) LOADM(mA, t+3);
  }
  WAITN(0); BAR; COMPUTE1(15, mB);

  // cross-lane then cross-pair row sum
  lrun += __shfl_xor(lrun, 32, 64);
  if (lane < 32) lrS[qt*64 + half*32 + l31] = lrun;
  LGKM0; BAR;
  lrun += lrS[qt*64 + (half^1)*32 + l31];
  const float invl = 1.0f / lrun;
  BAR;   // everyone done reading lrS before anything else touches LDS edges

  // ========== sweep 2: recompute, write attn, in-register P -> PV ==========
  f32x16 oacc[2];
#pragma unroll
  for (int t = 0; t < 2; t++)
    oacc[t] = (f32x16){0.f,0.f,0.f,0.f,0.f,0.f,0.f,0.f,0.f,0.f,0.f,0.f,0.f,0.f,0.f,0.f};

  auto compute2 = [&](int t){
    const int ks = t << 6;
    const char* sKc = lds + half*16384 + ((t & 1) << 13);
    const char* sVc = lds + 32768 + half*16384 + ((t & 1) << 13);
    const uint32_t bt = sMB[(t << 6) + lane];
#pragma unroll
    for (int Tt = 0; Tt < 2; Tt++){
      const int row = l31 + 32*Tt;
      const char* kr = sKc + row*128;
      const int sw = (row & 7) << 4;
      f32x16 acc = {0.f,0.f,0.f,0.f,0.f,0.f,0.f,0.f,0.f,0.f,0.f,0.f,0.f,0.f,0.f,0.f};
#pragma unroll
      for (int dc = 0; dc < 4; dc++){
        short8v ka = *(const short8v*)(kr + ((dc*32 + h16) ^ sw));
        acc = __builtin_amdgcn_mfma_f32_32x32x16_bf16(ka, qf[dc], acc, 0,0,0);
      }
      uint32_t pw[8];
#pragma unroll
      for (int u = 0; u < 4; u++){
        uint32_t nib = (bt >> ((Tt*4 + u)*4)) & 15u;
        float p0 = (nib & 1u) ? 0.f : exp2f(acc[4*u+0]) * invl;
        float p1 = (nib & 2u) ? 0.f : exp2f(acc[4*u+1]) * invl;
        float p2 = (nib & 4u) ? 0.f : exp2f(acc[4*u+2]) * invl;
        float p3 = (nib & 8u) ? 0.f : exp2f(acc[4*u+3]) * invl;
        f32x4 stv = { p0, p1, p2, p3 };
        *(f32x4*)(aRow + ks + 32*Tt + 8*u + h4) = stv;
        pw[2*u]   = pkbf(p0, p1);
        pw[2*u+1] = pkbf(p2, p3);
      }
#pragma unroll
      for (int c = 0; c < 2; c++){
        int4v wi = { (int)pw[4*c], (int)pw[4*c+1], (int)pw[4*c+2], (int)pw[4*c+3] };
        short8v pf = __builtin_bit_cast(short8v, wi);
#pragma unroll
        for (int T2 = 0; T2 < 2; T2++){
          const int vrow = l31 + 32*T2;
          short8v vf = *(const short8v*)(sVc + vrow*128 +
                         ((64*Tt + 32*c + h16) ^ ((vrow & 7) << 4)));
          oacc[T2] = __builtin_amdgcn_mfma_f32_32x32x16_bf16(vf, pf, oacc[T2], 0,0,0);
        }
      }
    }
  };

  ISSK(0); ISSV(0);
  WAITN(0); BAR; ISSK(1); ISSV(1); compute2(0);
  for (int t = 1; t < 16; ++t){
    WAITN(8); BAR;                 // drain KV(t); attn stores stay in flight
    if (t < 15){ ISSK(t+1); ISSV(t+1); }
    compute2(t);
  }

  // ===== pair-reduce oacc (half1 -> half0 via dead K/V LDS) and write O =====
  BAR;                              // all K/V reads done; region reusable
  char* pairScr = lds + qt*8192 + lane*128;
  if (half == 1){
    *(f32x16*)(pairScr)      = oacc[0];
    *(f32x16*)(pairScr + 64) = oacc[1];
  }
  LGKM0; BAR;
  if (half == 0){
    f32x16 o0 = oacc[0] + *(const f32x16*)(pairScr);
    f32x16 o1 = oacc[1] + *(const f32x16*)(pairScr + 64);
#pragma unroll
    for (int u = 0; u < 4; u++){
      f32x4 a0 = { o0[4*u+0], o0[4*u+1], o0[4*u+2], o0[4*u+3] };
      f32x4 a1 = { o1[4*u+0], o1[4*u+1], o1[4*u+2], o1[4*u+3] };
      *(f32x4*)(outp + ((size_t)b*S_ + qrow)*D_ +      8*u + h4) = a0;
      *(f32x4*)(outp + ((size_t)b*S_ + qrow)*D_ + 32 + 8*u + h4) = a1;
    }
  }
#undef LOADM
#undef COMPUTE1
}

extern "C" void kernel_launch(void* const* d_in, const int* in_sizes, int n_in,
                              void* d_out, int out_size, void* d_ws, size_t ws_size,
                              hipStream_t stream) {
  (void)in_sizes; (void)n_in; (void)out_size; (void)ws_size;
  const float* q    = (const float*)d_in[0];
  const float* k    = (const float*)d_in[1];
  const float* v    = (const float*)d_in[2];
  const int*   mask = (const int*)d_in[3];   // bool -> int32 per harness convention

  float* outp = (float*)d_out;
  float* attn = outp + (size_t)B_*S_*D_;     // outputs concatenated: output, attn

  short* qbuf = (short*)d_ws;                // 3 x 8.39MB bf16 scratch
  short* kbuf = qbuf + (size_t)B_*S_*D_;
  short* vbT  = kbuf + (size_t)B_*S_*D_;

  cvt_qk<<<4096, 256, 0, stream>>>(q, k, qbuf, kbuf);
  cvt_v<<<dim3(32, 32), 256, 0, stream>>>(v, vbT);
  attn_fused<<<dim3(8, 32), 1024, 0, stream>>>(qbuf, kbuf, vbT, mask, outp, attn);
}

// Round 12
// 451.408 us; speedup vs baseline: 1.0877x; 1.0877x over previous
//
#include <hip/hip_runtime.h>
#include <stdint.h>

#define B_ 32
#define S_ 2048
#define D_ 64
// q pre-scale: 1/8 (temperature) * log2(e) so exp2(acc) == exp(S/8)
#define QSCALE 0.18033688011112042f

typedef __attribute__((ext_vector_type(8))) short short8v;
typedef __attribute__((ext_vector_type(4))) short short4v;
typedef __attribute__((ext_vector_type(4))) float f32x4;
typedef __attribute__((ext_vector_type(4))) float float4v;
typedef __attribute__((ext_vector_type(4))) int int4v;

static __device__ inline short f2bf(float f){
  uint32_t u = __builtin_bit_cast(uint32_t, f);
  uint32_t r = (u + 0x7fffu + ((u >> 16) & 1u)) >> 16;
  return (short)(uint16_t)r;
}

static __device__ inline void gl16(const void* g, void* l){
  __builtin_amdgcn_global_load_lds(
      (const __attribute__((address_space(1))) void*)g,
      (__attribute__((address_space(3))) void*)l, 16, 0, 0);
}

static __device__ inline uint32_t pkbf(float lo, float hi){
  uint32_t w;
  asm("v_cvt_pk_bf16_f32 %0, %1, %2" : "=v"(w) : "v"(lo), "v"(hi));
  return w;
}

// ---- kernel 0a: q (pre-scaled by log2e/8) and k -> bf16 row-major ----
__global__ __launch_bounds__(256) void cvt_qk(const float* __restrict__ q,
                                              const float* __restrict__ k,
                                              short* __restrict__ qb,
                                              short* __restrict__ kb){
  size_t i = ((size_t)blockIdx.x * 256 + threadIdx.x) * 4;
  float4v a = *(const float4v*)(q + i);
  float4v c = *(const float4v*)(k + i);
  short4v qa = { f2bf(a[0]*QSCALE), f2bf(a[1]*QSCALE), f2bf(a[2]*QSCALE), f2bf(a[3]*QSCALE) };
  short4v kc = { f2bf(c[0]), f2bf(c[1]), f2bf(c[2]), f2bf(c[3]) };
  *(short4v*)(qb + i) = qa;
  *(short4v*)(kb + i) = kc;
}

// ---- kernel 0b: v -> bf16 transposed per batch: vbT[b][d][s] ----
__global__ __launch_bounds__(256) void cvt_v(const float* __restrict__ v,
                                             short* __restrict__ vbT){
  __shared__ float tile[64][65];
  int b = blockIdx.y, st = blockIdx.x;
  int tid = threadIdx.x;
#pragma unroll
  for (int i = 0; i < 4; i++){
    int s = tid + i*256;
    int row = s >> 4, c4 = (s & 15) * 4;
    float4v t = *(const float4v*)(v + ((size_t)b*S_ + st*64 + row)*D_ + c4);
    tile[row][c4+0] = t[0]; tile[row][c4+1] = t[1];
    tile[row][c4+2] = t[2]; tile[row][c4+3] = t[3];
  }
  __syncthreads();
#pragma unroll
  for (int i = 0; i < 2; i++){
    int s = tid + i*256;
    int d = s >> 3, s8 = (s & 7) * 8;
    short8v o;
#pragma unroll
    for (int j = 0; j < 8; j++) o[j] = f2bf(tile[s8 + j][d]);
    *(short8v*)(vbT + ((size_t)b*D_ + d)*S_ + st*64 + s8) = o;
  }
}

// ---- main fused kernel: 16 waves/CU, small write footprint per wave ----
// 256 thr (4 waves), 16 q/wave = 64 q/block, grid (32,32) = 1024 blocks,
// 40KB LDS => 4 blocks/CU. Mask: register int4 ping-pong prefetch (depth 2).
// Packed mask bits: 16 VGPRs (both sweeps fully unrolled -> static indexing).
// LDS: K dbuf 2x8K @0 | V dbuf 2x8K @16384 | P 4x2K @32768  (40960 B)
#define WAITN(n) asm volatile("s_waitcnt vmcnt(" #n ")" ::: "memory")
#define BAR   __builtin_amdgcn_s_barrier()

__global__ __launch_bounds__(256, 4) void attn_fused(
    const short* __restrict__ qb, const short* __restrict__ kb,
    const short* __restrict__ vbT, const int* __restrict__ mask,
    float* __restrict__ outp, float* __restrict__ attn)
{
  __shared__ __align__(16) char lds[40960];
  const int tid  = threadIdx.x;
  const int w    = tid >> 6;
  const int lane = tid & 63;
  const int lq   = lane & 15;
  const int g    = lane >> 4;
  const int woff = w << 10;          // per-wave 1KB slice of each DMA issue

  const int b   = blockIdx.y;
  const int q0b = blockIdx.x * 64;
  const int q0  = q0b + w*16;

  const short* kbb = kb  + (size_t)b*S_*D_;
  const short* vbb = vbT + (size_t)b*D_*S_;

  // K/V DMA source (2 issues x 256 thr x 16B = 8KB tile; src pre-swizzled)
  const int s0 = tid, s1 = 256 + tid;
  const int kr0 = s0 >> 3, kc0 = ((s0 & 7) ^ (kr0 & 7)) << 3;  // shorts
  const int kr1 = s1 >> 3, kc1 = ((s1 & 7) ^ (kr1 & 7)) << 3;
  const short* kSrc0 = kbb + (size_t)kr0*D_ + kc0;   // + ks*D_ per stage
  const short* kSrc1 = kbb + (size_t)kr1*D_ + kc1;
  const short* vSrc0 = vbb + (size_t)kr0*S_ + kc0;   // + ks per stage
  const short* vSrc1 = vbb + (size_t)kr1*S_ + kc1;

  // Q B-fragments (q pre-scaled by log2e/8)
  const size_t qoff = ((size_t)b*S_ + q0 + lq) * D_;
  const short8v qf0 = *(const short8v*)(qb + qoff + g*8);
  const short8v qf1 = *(const short8v*)(qb + qoff + 32 + g*8);

  const int* mrow = mask + ((size_t)b*S_ + q0 + lq) * S_;
  float* aRow = attn + ((size_t)b*S_ + q0 + lq) * S_;

  char* sP = lds + 32768 + (w << 11);       // wave-private 16 rows x 128B

  auto ISSK = [&](int s){ const size_t ks = (size_t)(s << 6); const int o = (s & 1) << 13;
    gl16(kSrc0 + ks*D_, lds + o +    0 + woff);
    gl16(kSrc1 + ks*D_, lds + o + 4096 + woff); };
  auto ISSV = [&](int s){ const size_t ks = (size_t)(s << 6); const int o = (s & 1) << 13;
    gl16(vSrc0 + ks, lds + 16384 + o +    0 + woff);
    gl16(vSrc1 + ks, lds + 16384 + o + 4096 + woff); };

#define LOADM(mv, s) do{ const int _ks = (s) << 6; \
    mv[0] = *(const int4v*)(mrow + _ks +  0 + g*4); \
    mv[1] = *(const int4v*)(mrow + _ks + 16 + g*4); \
    mv[2] = *(const int4v*)(mrow + _ks + 32 + g*4); \
    mv[3] = *(const int4v*)(mrow + _ks + 48 + g*4); }while(0)

  float lrun = 0.f;
  uint32_t bits32[16];               // packed mask bits, 2 stages per entry

  // ========== sweep 1: row sum of exp (max-free), pack mask bits ==========
  int4v mA[4], mB[4];
  ISSK(0); LOADM(mA, 0); LOADM(mB, 1);
  WAITN(8); BAR;                     // queue [K0(2) mA(4) mB(4)] -> drains K0
  {
    // st = 0 (uses mA)
    const char* sKc = lds;
    uint32_t bits = 0;
#pragma unroll
    for (int kkk = 0; kkk < 4; kkk++){
      const int r = (kkk<<4) + lq;
      short8v ka0 = *(const short8v*)(sKc + r*128 + (( g*16     ) ^ ((r & 7) << 4)));
      short8v ka1 = *(const short8v*)(sKc + r*128 + ((64 + g*16 ) ^ ((r & 7) << 4)));
      f32x4 acc = {0.f,0.f,0.f,0.f};
      acc = __builtin_amdgcn_mfma_f32_16x16x32_bf16(ka0, qf0, acc, 0,0,0);
      acc = __builtin_amdgcn_mfma_f32_16x16x32_bf16(ka1, qf1, acc, 0,0,0);
      int4v mu = mA[kkk];
      uint32_t nib = (mu[0]?1u:0u)|(mu[1]?2u:0u)|(mu[2]?4u:0u)|(mu[3]?8u:0u);
      bits |= nib << (kkk*4);
      float e0 = (nib & 1u) ? 0.f : exp2f(acc[0]);
      float e1 = (nib & 2u) ? 0.f : exp2f(acc[1]);
      float e2 = (nib & 4u) ? 0.f : exp2f(acc[2]);
      float e3 = (nib & 8u) ? 0.f : exp2f(acc[3]);
      lrun += (e0 + e1) + (e2 + e3);
    }
    bits32[0] = bits;
  }
  ISSK(1); LOADM(mA, 2);
#pragma unroll
  for (int st = 1; st < 32; ++st){
    if (st == 31) { WAITN(0); } else { WAITN(4); }   // drains K(st) in-order
    BAR;
    if (st < 31) ISSK(st+1);
    const char* sKc = lds + ((st & 1) << 13);
    uint32_t bits = 0;
#pragma unroll
    for (int kkk = 0; kkk < 4; kkk++){
      const int r = (kkk<<4) + lq;
      short8v ka0 = *(const short8v*)(sKc + r*128 + (( g*16     ) ^ ((r & 7) << 4)));
      short8v ka1 = *(const short8v*)(sKc + r*128 + ((64 + g*16 ) ^ ((r & 7) << 4)));
      f32x4 acc = {0.f,0.f,0.f,0.f};
      acc = __builtin_amdgcn_mfma_f32_16x16x32_bf16(ka0, qf0, acc, 0,0,0);
      acc = __builtin_amdgcn_mfma_f32_16x16x32_bf16(ka1, qf1, acc, 0,0,0);
      int4v mu = (st & 1) ? mB[kkk] : mA[kkk];
      uint32_t nib = (mu[0]?1u:0u)|(mu[1]?2u:0u)|(mu[2]?4u:0u)|(mu[3]?8u:0u);
      bits |= nib << (kkk*4);
      float e0 = (nib & 1u) ? 0.f : exp2f(acc[0]);
      float e1 = (nib & 2u) ? 0.f : exp2f(acc[1]);
      float e2 = (nib & 4u) ? 0.f : exp2f(acc[2]);
      float e3 = (nib & 8u) ? 0.f : exp2f(acc[3]);
      lrun += (e0 + e1) + (e2 + e3);
    }
    if (st & 1) bits32[st>>1] |= bits << 16; else bits32[st>>1] = bits;
    if (st + 2 < 32){
      if (st & 1) { LOADM(mB, st+2); } else { LOADM(mA, st+2); }
    }
  }

  lrun += __shfl_xor(lrun, 16, 64);
  lrun += __shfl_xor(lrun, 32, 64);
  const float invl = 1.0f / lrun;

  // ========== sweep 2: recompute, write attn, accumulate PV ==========
  f32x4 oacc[4];
#pragma unroll
  for (int n = 0; n < 4; n++) oacc[n] = (f32x4){0.f,0.f,0.f,0.f};

  auto compute2 = [&](int st){
    const int ks = st << 6;
    const char* sKc = lds + ((st & 1) << 13);
    const char* sVc = lds + 16384 + ((st & 1) << 13);
    const uint32_t bt = (bits32[st>>1] >> ((st & 1) * 16)) & 0xffffu;
#pragma unroll
    for (int c = 0; c < 2; c++){
#pragma unroll
      for (int t2 = 0; t2 < 2; t2++){
        const int kkk = c*2 + t2;
        const int r = (kkk<<4) + lq;
        short8v ka0 = *(const short8v*)(sKc + r*128 + (( g*16     ) ^ ((r & 7) << 4)));
        short8v ka1 = *(const short8v*)(sKc + r*128 + ((64 + g*16 ) ^ ((r & 7) << 4)));
        f32x4 acc = {0.f,0.f,0.f,0.f};
        acc = __builtin_amdgcn_mfma_f32_16x16x32_bf16(ka0, qf0, acc, 0,0,0);
        acc = __builtin_amdgcn_mfma_f32_16x16x32_bf16(ka1, qf1, acc, 0,0,0);
        uint32_t m4 = (bt >> (kkk*4)) & 15u;
        float p0 = (m4 & 1u) ? 0.f : exp2f(acc[0]) * invl;
        float p1 = (m4 & 2u) ? 0.f : exp2f(acc[1]) * invl;
        float p2 = (m4 & 4u) ? 0.f : exp2f(acc[2]) * invl;
        float p3 = (m4 & 8u) ? 0.f : exp2f(acc[3]) * invl;
        f32x4 stv = { p0, p1, p2, p3 };
        *(f32x4*)(aRow + ks + kkk*16 + g*4) = stv;
        uint32_t w0 = pkbf(p0, p1), w1 = pkbf(p2, p3);
        *(uint32_t*)(sP + lq*128 + (((t2*32 + g*8    ) ^ ((lq & 7) << 4))) ) = w0;
        *(uint32_t*)(sP + lq*128 + (((t2*32 + g*8 + 4) ^ ((lq & 7) << 4))) ) = w1;
      }
      short8v pf = *(const short8v*)(sP + lq*128 + ((g*16) ^ ((lq & 7) << 4)));
#pragma unroll
      for (int n = 0; n < 4; n++){
        const int dr = lq + 16*n;
        short8v vf = *(const short8v*)(sVc + dr*128 + ((c*64 + g*16) ^ ((dr & 7) << 4)));
        oacc[n] = __builtin_amdgcn_mfma_f32_16x16x32_bf16(pf, vf, oacc[n], 0,0,0);
      }
    }
  };

  ISSK(0); ISSV(0);
  WAITN(0); BAR;                     // KV0 landed (nothing else outstanding)
  ISSK(1); ISSV(1);
  compute2(0);
#pragma unroll
  for (int st = 1; st < 32; ++st){
    if (st == 31) { WAITN(0); } else { WAITN(8); }  // drains KV(st) in-order
    BAR;
    if (st < 31){ ISSK(st+1); ISSV(st+1); }
    compute2(st);
  }

  // epilogue: O[q = q0 + 4g + reg][d = lq + 16n]
#pragma unroll
  for (int n = 0; n < 4; n++){
#pragma unroll
    for (int r2 = 0; r2 < 4; r2++){
      outp[((size_t)b*S_ + q0 + 4*g + r2)*D_ + lq + 16*n] = oacc[n][r2];
    }
  }
#undef LOADM
}

extern "C" void kernel_launch(void* const* d_in, const int* in_sizes, int n_in,
                              void* d_out, int out_size, void* d_ws, size_t ws_size,
                              hipStream_t stream) {
  (void)in_sizes; (void)n_in; (void)out_size; (void)ws_size;
  const float* q    = (const float*)d_in[0];
  const float* k    = (const float*)d_in[1];
  const float* v    = (const float*)d_in[2];
  const int*   mask = (const int*)d_in[3];   // bool -> int32 per harness convention

  float* outp = (float*)d_out;
  float* attn = outp + (size_t)B_*S_*D_;     // outputs concatenated: output, attn

  short* qbuf = (short*)d_ws;                // 3 x 8.39MB bf16 scratch
  short* kbuf = qbuf + (size_t)B_*S_*D_;
  short* vbT  = kbuf + (size_t)B_*S_*D_;

  cvt_qk<<<4096, 256, 0, stream>>>(q, k, qbuf, kbuf);
  cvt_v<<<dim3(32, 32), 256, 0, stream>>>(v, vbT);
  attn_fused<<<dim3(32, 32), 256, 0, stream>>>(qbuf, kbuf, vbT, mask, outp, attn);
}